// Round 8
// baseline (222.344 us; speedup 1.0000x reference)
//
#include <hip/hip_runtime.h>

#define NODES 128
#define NFEAT 256
#define BATCH 512
#define KTOT  (NODES * NFEAT)   // 32768, stage-3 K
#define SPLIT 64                // stage-3 split-K factor
#define KCH   (KTOT / SPLIT)    // 512 per chunk

typedef __bf16 bf16_t;
typedef bf16_t bf16x4 __attribute__((ext_vector_type(4)));
typedef bf16_t bf16x8 __attribute__((ext_vector_type(8)));
typedef float  f32x4  __attribute__((ext_vector_type(4)));

#define BK    32
#define LDK   40     // bf16 LDS row stride, 32-wide tiles (80B)
#define BK2   64
#define LDK2  72     // bf16 LDS row stride, 64-wide tiles (144B)
#define LDM   136    // Sb row stride
#define TILE  128

// Workgroup barrier WITHOUT the vmcnt(0) drain __syncthreads() emits.
// Only LDS (lgkmcnt) visibility is needed; global loads/stores stay in flight.
__device__ __forceinline__ void bar() {
    asm volatile("s_waitcnt lgkmcnt(0)\n\ts_barrier" ::: "memory");
}

__device__ __forceinline__ bf16x8 cvt8(const float4 a, const float4 b) {
    bf16x8 t;
    t[0] = (bf16_t)a.x; t[1] = (bf16_t)a.y; t[2] = (bf16_t)a.z; t[3] = (bf16_t)a.w;
    t[4] = (bf16_t)b.x; t[5] = (bf16_t)b.y; t[6] = (bf16_t)b.z; t[7] = (bf16_t)b.w;
    return t;
}

// ---- fp32 128x32 tile: reg-load / LDS-store ----
struct XT { float4 v[4]; };
__device__ __forceinline__ void xload(const float* __restrict__ src, int ld, int k0,
                                      int tid, XT& t) {
#pragma unroll
    for (int i = 0; i < 2; i++) {
        int f = tid + i * 256, r = f >> 2, c = f & 3;
        t.v[2 * i]     = *(const float4*)(src + (size_t)r * ld + k0 + c * 8);
        t.v[2 * i + 1] = *(const float4*)(src + (size_t)r * ld + k0 + c * 8 + 4);
    }
}
__device__ __forceinline__ void xstore(bf16_t* __restrict__ dst, int tid, const XT& t) {
#pragma unroll
    for (int i = 0; i < 2; i++) {
        int f = tid + i * 256, r = f >> 2, c = f & 3;
        *(bf16x8*)(dst + r * LDK + c * 8) = cvt8(t.v[2 * i], t.v[2 * i + 1]);
    }
}

// ---- fp32 128x64 tile (k_out B) ----
struct XT2 { float4 v[8]; };
__device__ __forceinline__ void xload2(const float* __restrict__ src, int ld, int k0,
                                       int tid, XT2& t) {
#pragma unroll
    for (int i = 0; i < 4; i++) {
        int f = tid + i * 256, r = f >> 3, c = f & 7;
        t.v[2 * i]     = *(const float4*)(src + (size_t)r * ld + k0 + c * 8);
        t.v[2 * i + 1] = *(const float4*)(src + (size_t)r * ld + k0 + c * 8 + 4);
    }
}
__device__ __forceinline__ void xstore2(bf16_t* __restrict__ dst, int tid, const XT2& t) {
#pragma unroll
    for (int i = 0; i < 4; i++) {
        int f = tid + i * 256, r = f >> 3, c = f & 7;
        *(bf16x8*)(dst + r * LDK2 + c * 8) = cvt8(t.v[2 * i], t.v[2 * i + 1]);
    }
}

// ---- bf16 128x64 tile (k_out A) ----
struct AT2 { bf16x8 v[4]; };
__device__ __forceinline__ void aload2(const bf16_t* __restrict__ src, int ld, int k0,
                                       int tid, AT2& t) {
#pragma unroll
    for (int i = 0; i < 4; i++) {
        int f = tid + i * 256, r = f >> 3, c = f & 7;
        t.v[i] = *(const bf16x8*)(src + (size_t)r * ld + k0 + c * 8);
    }
}
__device__ __forceinline__ void astore2(bf16_t* __restrict__ dst, int tid, const AT2& t) {
#pragma unroll
    for (int i = 0; i < 4; i++) {
        int f = tid + i * 256, r = f >> 3, c = f & 7;
        *(bf16x8*)(dst + r * LDK2 + c * 8) = t.v[i];
    }
}

// ---- pre-transpose gcn_w[k][g] -> wT[g][k] bf16 ----
__global__ __launch_bounds__(256)
void k_wt(const float* __restrict__ w, bf16_t* __restrict__ wT) {
    const int g0 = blockIdx.x * 4;
    const int k  = threadIdx.x;
    const float4 v = *(const float4*)(w + (size_t)k * NFEAT + g0);
    wT[(size_t)(g0 + 0) * NFEAT + k] = (bf16_t)v.x;
    wT[(size_t)(g0 + 1) * NFEAT + k] = (bf16_t)v.y;
    wT[(size_t)(g0 + 2) * NFEAT + k] = (bf16_t)v.z;
    wT[(size_t)(g0 + 3) * NFEAT + k] = (bf16_t)v.w;
}

// ---- fused stages 1+2: 2 batches per block (persistent-ish), R5 loop idiom ----
__global__ __launch_bounds__(256, 3)
void k_fused12(const float* __restrict__ x, const float* __restrict__ adj,
               const bf16_t* __restrict__ wT, const float* __restrict__ gcn_b,
               bf16_t* __restrict__ mid) {
    __shared__ __align__(16) bf16_t As[TILE * LDK];   // 10.2 KB
    __shared__ __align__(16) bf16_t Sb[TILE * LDM];   // 34.8 KB
    const int n0  = blockIdx.x * TILE;   // g-tile (0 or 128)
    const int tid = threadIdx.x;
    const int lane = tid & 63, w = tid >> 6, wm = w & 1, wn = w >> 1;
    const int l15 = lane & 15, q = lane >> 4;

    const bf16_t* wrow[4];
#pragma unroll
    for (int j = 0; j < 4; j++)
        wrow[j] = wT + (size_t)(n0 + wn * 64 + j * 16 + l15) * NFEAT + q * 8;

    for (int bb = 0; bb < 2; bb++) {
        const int b = blockIdx.y * 2 + bb;
        const float* xb   = x   + (size_t)b * NODES * NFEAT;
        const float* adjb = adj + (size_t)b * NODES * NODES;

        // ---- stage 1: S = x[b] @ W  (K=256, 8 iters, dist-2) ----
        f32x4 acc[4][4] = {};
        {
            XT r0, rn, r2;
            xload(xb, NFEAT, 0, tid, r0);
            xload(xb, NFEAT, BK, tid, rn);
            bf16x8 bcur[4], bnxt[4];
#pragma unroll
            for (int j = 0; j < 4; j++) bcur[j] = *(const bf16x8*)(wrow[j]);
            bar();                       // prev batch's Sb reads done before As reuse
            xstore(As, tid, r0);
            bar();
            for (int k0 = 0; k0 < NFEAT; k0 += BK) {
                const bool in1 = (k0 + BK)   < NFEAT;
                const bool in2 = (k0 + 2*BK) < NFEAT;
                if (in2) xload(xb, NFEAT, k0 + 2*BK, tid, r2);
                const int knc = in1 ? k0 + BK : 0;
#pragma unroll
                for (int j = 0; j < 4; j++) bnxt[j] = *(const bf16x8*)(wrow[j] + knc);
                bf16x8 a[4];
#pragma unroll
                for (int i = 0; i < 4; i++)
                    a[i] = *(const bf16x8*)(As + (wm * 64 + i * 16 + l15) * LDK + q * 8);
#pragma unroll
                for (int i = 0; i < 4; i++)
#pragma unroll
                    for (int j = 0; j < 4; j++)
                        acc[i][j] = __builtin_amdgcn_mfma_f32_16x16x32_bf16(a[i], bcur[j], acc[i][j], 0, 0, 0);
                bar();
                if (in1) xstore(As, tid, rn);
                rn = r2;
#pragma unroll
                for (int j = 0; j < 4; j++) bcur[j] = bnxt[j];
                bar();
            }
        }

        // stage-2 tiles 0,1 in flight while writing Sb
        XT a0, a1, a2;
        xload(adjb, NODES, 0, tid, a0);
        xload(adjb, NODES, BK, tid, a1);
#pragma unroll
        for (int i = 0; i < 4; i++)
#pragma unroll
            for (int j = 0; j < 4; j++)
#pragma unroll
                for (int rr = 0; rr < 4; rr++) {
                    int m = wm * 64 + i * 16 + q * 4 + rr;
                    int g = wn * 64 + j * 16 + l15;
                    Sb[g * LDM + m] = (bf16_t)acc[i][j][rr];
                }
        bar();                           // stage-1 As reads done + Sb visible
        xstore(As, tid, a0);
        bar();

        // ---- stage 2: mid = adj[b] @ S  (K=128, 4 iters, dist-2) ----
        f32x4 acc2[4][4] = {};
        for (int k0 = 0; k0 < NODES; k0 += BK) {
            const bool in1 = (k0 + BK)   < NODES;
            const bool in2 = (k0 + 2*BK) < NODES;
            if (in2) xload(adjb, NODES, k0 + 2*BK, tid, a2);
            bf16x8 a[4], bb2[4];
#pragma unroll
            for (int i = 0; i < 4; i++)
                a[i] = *(const bf16x8*)(As + (wm * 64 + i * 16 + l15) * LDK + q * 8);
#pragma unroll
            for (int j = 0; j < 4; j++)
                bb2[j] = *(const bf16x8*)(Sb + (wn * 64 + j * 16 + l15) * LDM + k0 + q * 8);
#pragma unroll
            for (int i = 0; i < 4; i++)
#pragma unroll
                for (int j = 0; j < 4; j++)
                    acc2[i][j] = __builtin_amdgcn_mfma_f32_16x16x32_bf16(a[i], bb2[j], acc2[i][j], 0, 0, 0);
            bar();
            if (in1) xstore(As, tid, a1);
            a1 = a2;
            bar();
        }
        // epilogue: + gcn_b -> mid[b][node][g]  (stores overlap next batch's loads)
        bf16_t* outb = mid + (size_t)b * NODES * NFEAT;
#pragma unroll
        for (int j = 0; j < 4; j++) {
            int g = n0 + wn * 64 + j * 16 + l15;
            float bias = gcn_b[g];
#pragma unroll
            for (int i = 0; i < 4; i++)
#pragma unroll
                for (int rr = 0; rr < 4; rr++) {
                    int node = wm * 64 + i * 16 + q * 4 + rr;
                    outb[(size_t)node * NFEAT + g] = (bf16_t)(acc2[i][j][rr] + bias);
                }
        }
    }
}

// ---- stage 3: split-K=64, BK=64, single-barrier LDS dbuf, explicit cur/nxt ----
__global__ __launch_bounds__(256, 2)
void k_out(const bf16_t* __restrict__ flat, const float* __restrict__ fcw,
           bf16_t* __restrict__ part) {
    __shared__ __align__(16) bf16_t As[2][TILE * LDK2];  // 2 x 18.4 KB
    __shared__ __align__(16) bf16_t Bs[2][TILE * LDK2];  // 2 x 18.4 KB
    const int m0 = blockIdx.x * TILE;
    const int n0 = blockIdx.y * TILE;
    const int kb = blockIdx.z * KCH;     // 8 iters of BK2
    const int tid = threadIdx.x;
    const int lane = tid & 63, w = tid >> 6, wm = w & 1, wn = w >> 1;
    const int l15 = lane & 15, q = lane >> 4;
    f32x4 acc[4][4] = {};
    const bf16_t* fa = flat + (size_t)m0 * KTOT;
    const float*  fb = fcw + (size_t)n0 * KTOT;

    AT2 acur, anxt; XT2 bcur, bnxt;
    aload2(fa, KTOT, kb, tid, acur);
    xload2(fb, KTOT, kb, tid, bcur);
    aload2(fa, KTOT, kb + BK2, tid, anxt);
    xload2(fb, KTOT, kb + BK2, tid, bnxt);
    astore2(As[0], tid, acur);
    xstore2(Bs[0], tid, bcur);
    bar();
#pragma unroll 2
    for (int k = 0; k < 8; k++) {
        const bool in2 = k + 2 < 8;
        AT2 a2; XT2 b2;
        if (in2) { aload2(fa, KTOT, kb + (k + 2) * BK2, tid, a2);
                   xload2(fb, KTOT, kb + (k + 2) * BK2, tid, b2); }
#pragma unroll
        for (int kk = 0; kk < BK2; kk += BK) {
            bf16x8 a[4], bbf[4];
#pragma unroll
            for (int i = 0; i < 4; i++)
                a[i] = *(const bf16x8*)(&As[k & 1][(wm * 64 + i * 16 + l15) * LDK2 + kk + q * 8]);
#pragma unroll
            for (int j = 0; j < 4; j++)
                bbf[j] = *(const bf16x8*)(&Bs[k & 1][(wn * 64 + j * 16 + l15) * LDK2 + kk + q * 8]);
#pragma unroll
            for (int i = 0; i < 4; i++)
#pragma unroll
                for (int j = 0; j < 4; j++)
                    acc[i][j] = __builtin_amdgcn_mfma_f32_16x16x32_bf16(a[i], bbf[j], acc[i][j], 0, 0, 0);
        }
        if (k + 1 < 8) {
            astore2(As[(k + 1) & 1], tid, anxt);
            xstore2(Bs[(k + 1) & 1], tid, bnxt);
        }
        anxt = a2; bnxt = b2;
        bar();
    }
    bf16_t* pb = part + (size_t)blockIdx.z * BATCH * NFEAT;
#pragma unroll
    for (int i = 0; i < 4; i++)
#pragma unroll
        for (int j = 0; j < 4; j++)
#pragma unroll
            for (int r = 0; r < 4; r++) {
                int bt_ = m0 + wm * 64 + i * 16 + q * 4 + r;
                int o   = n0 + wn * 64 + j * 16 + l15;
                pb[(size_t)bt_ * NFEAT + o] = (bf16_t)acc[i][j][r];
            }
}

// ---- stage 4: reduce bf16 partials + fc_b -> slots 0,2; x[:,0,:] -> slot 1 ----
__global__ __launch_bounds__(256)
void k_reduce(const bf16_t* __restrict__ part, const float* __restrict__ fc_b,
              const float* __restrict__ x, float* __restrict__ out) {
    const int g2 = (blockIdx.x * 256 + threadIdx.x) * 2;   // 256 blocks
    const int o = g2 & (NFEAT - 1), b = g2 >> 8;
    float s0 = fc_b[o], s1 = fc_b[o + 1];
#pragma unroll 16
    for (int i = 0; i < SPLIT; i++) {
        bf16_t p0 = part[(size_t)i * BATCH * NFEAT + g2];
        bf16_t p1 = part[(size_t)i * BATCH * NFEAT + g2 + 1];
        s0 += (float)p0; s1 += (float)p1;
    }
    out[g2] = s0; out[g2 + 1] = s1;
    out[2 * BATCH * NFEAT + g2] = s0; out[2 * BATCH * NFEAT + g2 + 1] = s1;
    out[BATCH * NFEAT + g2]     = x[(size_t)b * NODES * NFEAT + o];
    out[BATCH * NFEAT + g2 + 1] = x[(size_t)b * NODES * NFEAT + o + 1];
}

extern "C" void kernel_launch(void* const* d_in, const int* in_sizes, int n_in,
                              void* d_out, int out_size, void* d_ws, size_t ws_size,
                              hipStream_t stream) {
    const float* x     = (const float*)d_in[0];
    const float* adj   = (const float*)d_in[1];
    const float* gcn_w = (const float*)d_in[2];
    const float* gcn_b = (const float*)d_in[3];
    const float* fc_w  = (const float*)d_in[4];
    const float* fc_b  = (const float*)d_in[5];
    float* out = (float*)d_out;

    // ws: wT 128KB | mid 33.5MB | part (bf16) 16.8MB  => ~50.5 MB
    bf16_t* wT   = (bf16_t*)d_ws;
    bf16_t* mid  = (bf16_t*)((char*)d_ws + 131072);
    bf16_t* part = (bf16_t*)((char*)d_ws + 131072 + (size_t)BATCH * NODES * NFEAT * 2);

    k_wt     <<<dim3(64), dim3(256), 0, stream>>>(gcn_w, wT);
    k_fused12<<<dim3(2, 256), dim3(256), 0, stream>>>(x, adj, wT, gcn_b, mid);
    k_out    <<<dim3(4, 2, SPLIT), dim3(256), 0, stream>>>(mid, fc_w, part);
    k_reduce <<<dim3(256), dim3(256), 0, stream>>>(part, fc_b, x, out);
}